// Round 13
// baseline (380.224 us; speedup 1.0000x reference)
//
#include <hip/hip_runtime.h>
#include <hip/hip_fp16.h>
#include <math.h>

#define NEG_SLOPE 0.2f
#define GAT_EPS 1e-16f

__device__ __forceinline__ float elu_f(float x) { return x > 0.f ? x : expm1f(x); }
__device__ __forceinline__ float lrelu_f(float x) { return x > 0.f ? x : NEG_SLOPE * x; }

typedef _Float16 half2v __attribute__((ext_vector_type(2)));

// fp32 accumulate of half2 dot: acc += v.x*a.x + v.y*a.y
__device__ __forceinline__ float fdot2f(unsigned int v, unsigned int a, float acc) {
#if __has_builtin(__builtin_amdgcn_fdot2)
    return __builtin_amdgcn_fdot2(__builtin_bit_cast(half2v, v),
                                  __builtin_bit_cast(half2v, a), acc, false);
#else
    __half2 hv = __builtin_bit_cast(__half2, v);
    __half2 ha = __builtin_bit_cast(__half2, a);
    float2 fv = __half22float2(hv), fa = __half22float2(ha);
    return fmaf(fv.x, fa.x, fmaf(fv.y, fa.y, acc));
#endif
}

__device__ __forceinline__ unsigned int pack_half2(float a, float b) {
    __half2 h = __floats2half2_rn(a, b);
    return __builtin_bit_cast(unsigned int, h);
}

__device__ __forceinline__ float waveReduceSum(float v) {
    #pragma unroll
    for (int off = 32; off > 0; off >>= 1) v += __shfl_xor(v, off, 64);
    return v;
}

// ---------------- init: zero deg/sums/cnts; last block also folds attention vectors ----------------
__global__ void init_kernel(int* deg, float* sums, float* cnts, int N, int G,
        const float* __restrict__ W1, const float* __restrict__ as1, const float* __restrict__ ad1,
        const float* __restrict__ W2, const float* __restrict__ as2, const float* __restrict__ ad2,
        float* __restrict__ wa1, float* __restrict__ wd1,
        float* __restrict__ wa2, float* __restrict__ wd2) {
    int i = blockIdx.x * 256 + threadIdx.x;
    if (i < N) deg[i] = 0;
    if (i < G * 128) sums[i] = 0.f;
    if (i < G) cnts[i] = 0.f;
    if (blockIdx.x == gridDim.x - 1) {
        int t = threadIdx.x;
        if (t < 64) {                      // layer1: h=t>>5, c=t&31
            int h = t >> 5, c = t & 31;
            const float* w = W1 + (h * 32 + c) * 64;
            float sa = 0.f, sd = 0.f;
            for (int o = 0; o < 64; ++o) {
                sa = fmaf(w[o], as1[h * 64 + o], sa);
                sd = fmaf(w[o], ad1[h * 64 + o], sd);
            }
            wa1[t] = sa; wd1[t] = sd;
        } else if (t < 192) {              // layer2: u=t-64, h=u>>6, c=u&63
            int u = t - 64, h = u >> 6, c = u & 63;
            const float* w = W2 + (h * 64 + c) * 128;
            float sa = 0.f, sd = 0.f;
            for (int o = 0; o < 128; ++o) {
                sa = fmaf(w[o], as2[h * 128 + o], sa);
                sd = fmaf(w[o], ad2[h * 128 + o], sd);
            }
            wa2[u] = sa; wd2[u] = sd;
        }
    }
}

// ---------------- CSR build ----------------
__global__ __launch_bounds__(256) void hist_kernel(const int* __restrict__ dst,
                                                   int* __restrict__ deg, int E) {
    int e = blockIdx.x * 256 + threadIdx.x;
    if (e < E) atomicAdd(&deg[dst[e]], 1);
}

__global__ __launch_bounds__(256) void scan_blocks_kernel(const int* __restrict__ deg,
        int* __restrict__ ofs, int* __restrict__ bsum, int N) {
    __shared__ int wtot[4];
    int tid = threadIdx.x, lane = tid & 63, wid = tid >> 6;
    int i = blockIdx.x * 256 + tid;
    int v = (i < N) ? deg[i] : 0;
    int incl = v;
    #pragma unroll
    for (int off = 1; off < 64; off <<= 1) {
        int t = __shfl_up(incl, off, 64);
        if (lane >= off) incl += t;
    }
    if (lane == 63) wtot[wid] = incl;
    __syncthreads();
    int woff = 0;
    #pragma unroll
    for (int w = 0; w < 4; ++w) if (w < wid) woff += wtot[w];
    int excl = incl - v + woff;
    if (i < N) ofs[i] = excl;
    if (tid == 255) bsum[blockIdx.x] = woff + incl;
}

__global__ __launch_bounds__(1024) void scan_bsum_kernel(const int* __restrict__ bsum,
        int* __restrict__ bofs, int* __restrict__ ofsN, int nb) {
    __shared__ int wsum[16];
    int tid = threadIdx.x, lane = tid & 63, wid = tid >> 6;
    int v = (tid < nb) ? bsum[tid] : 0;
    int incl = v;
    #pragma unroll
    for (int off = 1; off < 64; off <<= 1) {
        int t = __shfl_up(incl, off, 64);
        if (lane >= off) incl += t;
    }
    if (lane == 63) wsum[wid] = incl;
    __syncthreads();
    if (wid == 0) {
        int wv = (lane < 16) ? wsum[lane] : 0;
        int winc = wv;
        #pragma unroll
        for (int off = 1; off < 16; off <<= 1) {
            int t = __shfl_up(winc, off, 64);
            if (lane >= off) winc += t;
        }
        if (lane < 16) wsum[lane] = winc - wv;
    }
    __syncthreads();
    int excl = incl - v + wsum[wid];
    if (tid < nb) bofs[tid] = excl;
    if (tid == nb - 1) *ofsN = excl + v;
}

__global__ __launch_bounds__(256) void scan_add_kernel(int* __restrict__ ofs,
        const int* __restrict__ bofs, int* __restrict__ cursor, int N) {
    int i = blockIdx.x * 256 + threadIdx.x;
    if (i < N) {
        int v = ofs[i] + bofs[blockIdx.x];
        ofs[i] = v;
        cursor[i] = v;
    }
}

__global__ __launch_bounds__(256) void scatter_kernel(
        const int* __restrict__ src, const int* __restrict__ dst,
        int* __restrict__ cursor, int* __restrict__ sperm, int E) {
    int e = blockIdx.x * 256 + threadIdx.x;
    if (e >= E) return;
    int d = dst[e];
    int pos = atomicAdd(&cursor[d], 1);
    sperm[pos] = src[e];
}

// ---------------- fused fc0 + GAT layer1 transform (8 nodes/block) ----------------
__global__ __launch_bounds__(256) void fused_t1(
        const float* __restrict__ x, const float* __restrict__ w0,
        const float* __restrict__ b0, const float* __restrict__ W1,
        const float* __restrict__ wa1, const float* __restrict__ wd1,
        __half* __restrict__ h1, float* __restrict__ es, float* __restrict__ ed, int N) {
    __shared__ float xs[8 * 16];
    __shared__ float hs[8 * 32];
    int n0 = blockIdx.x * 8;
    int tid = threadIdx.x;
    if (tid < 128) {
        int gi = n0 * 16 + tid;
        xs[tid] = (gi < N * 16) ? x[gi] : 0.f;
    }
    __syncthreads();
    {
        int j = tid >> 5, o = tid & 31;
        float acc = b0[o];
        #pragma unroll
        for (int c = 0; c < 16; ++c) acc = fmaf(xs[j * 16 + c], w0[c * 32 + o], acc);
        hs[j * 32 + o] = elu_f(acc);
    }
    __syncthreads();
    int o = tid & 63, h = (tid >> 6) & 1, nh = tid >> 7;
    float acc[4];
    #pragma unroll
    for (int j = 0; j < 4; ++j) acc[j] = 0.f;
    const float* wp = W1 + h * (32 * 64) + o;
    #pragma unroll
    for (int c = 0; c < 32; ++c) {
        float wv = wp[c * 64];
        #pragma unroll
        for (int j = 0; j < 4; ++j) acc[j] = fmaf(hs[(nh * 4 + j) * 32 + c], wv, acc[j]);
    }
    #pragma unroll
    for (int j = 0; j < 4; ++j) {
        int n = n0 + nh * 4 + j;
        if (n < N) h1[(size_t)n * 128 + 2 * o + h] = __float2half(acc[j]);
    }
    if (tid < 32) {
        int n = tid >> 2, r = tid & 3, hh = r >> 1, isd = r & 1;
        const float* wv = (isd ? wd1 : wa1) + hh * 32;
        float s = 0.f;
        #pragma unroll
        for (int c = 0; c < 32; ++c) s = fmaf(hs[n * 32 + c], wv[c], s);
        int nn = n0 + n;
        if (nn < N) { if (isd) ed[nn * 2 + hh] = s; else es[nn * 2 + hh] = s; }
    }
}

// ---------------- fused agg-layer1 + transform-layer2: block = 8 nodes ----------------
// phase A: 4 waves x 2 nodes, aggregate layer1 (no segment-max; exact by shift-invariance)
//          into LDS xs (pre-activated with b1).
// phase B: transform2 on the LDS tile; h2 fp16 packed (half idx n*256 + 2*o + h); es2/ed2.
// NOTE: h1/es1/ed1 and h2/es2/ed2 MUST be distinct buffers — blocks overlap phases.
__global__ __launch_bounds__(256) void gat_mid(
        const int* __restrict__ ofs, const int* __restrict__ sperm,
        const float* __restrict__ es, const float* __restrict__ ed,
        const unsigned int* __restrict__ h1, const float* __restrict__ b1,
        const float* __restrict__ W, const float* __restrict__ wa2,
        const float* __restrict__ wd2, __half* __restrict__ h2,
        float* __restrict__ es2, float* __restrict__ ed2, int N) {
    __shared__ float xs[8 * 64];
    __shared__ uint2 meta[4][64];
    int w = threadIdx.x >> 6;
    int lane = threadIdx.x & 63;
    int n0 = blockIdx.x * 8;
    int tid = threadIdx.x;

    // ---- phase A ----
    #pragma unroll
    for (int it = 0; it < 2; ++it) {
        int d = n0 + w * 2 + it;
        if (d < N) {
            int beg = ofs[d], end = ofs[d + 1];
            int deg = end - beg;
            float2 edv = *reinterpret_cast<const float2*>(ed + (size_t)d * 2);
            int s_f = 0;
            float ex0 = 0.f, ex1 = 0.f;
            int i0 = beg + lane;
            if (i0 < end) {
                s_f = sperm[i0];
                float2 esv = *reinterpret_cast<const float2*>(es + (size_t)s_f * 2);
                ex0 = __expf(lrelu_f(esv.x + edv.x));
                ex1 = __expf(lrelu_f(esv.y + edv.y));
            }
            float s0 = ex0, s1 = ex1;
            for (int i = i0 + 64; i < end; i += 64) {
                int s = sperm[i];
                float2 esv = *reinterpret_cast<const float2*>(es + (size_t)s * 2);
                s0 += __expf(lrelu_f(esv.x + edv.x));
                s1 += __expf(lrelu_f(esv.y + edv.y));
            }
            s0 = waveReduceSum(s0);
            s1 = waveReduceSum(s1);
            float r0 = 0.5f / (s0 + GAT_EPS), r1 = 0.5f / (s1 + GAT_EPS);
            int jmax = deg < 64 ? deg : 64;
            if (lane < jmax)
                meta[w][lane] = make_uint2((unsigned int)s_f, pack_half2(ex0 * r0, ex1 * r1));
            // wave-internal LDS write->read; lgkmcnt ordering, no barrier needed

            float acc = 0.f;
            int j = 0;
            for (; j + 4 <= jmax; j += 4) {
                uint2 mm[4]; unsigned int vv[4];
                #pragma unroll
                for (int k = 0; k < 4; ++k) mm[k] = meta[w][j + k];
                #pragma unroll
                for (int k = 0; k < 4; ++k) vv[k] = h1[(size_t)mm[k].x * 64 + lane];
                #pragma unroll
                for (int k = 0; k < 4; ++k) acc = fdot2f(vv[k], mm[k].y, acc);
            }
            for (; j < jmax; ++j) {
                uint2 m = meta[w][j];
                acc = fdot2f(h1[(size_t)m.x * 64 + lane], m.y, acc);
            }
            for (int i = beg + 64; i < end; ++i) {  // rare: deg > 64
                int s = sperm[i];
                float2 esv = *reinterpret_cast<const float2*>(es + (size_t)s * 2);
                float a0 = __expf(lrelu_f(esv.x + edv.x)) * r0;
                float a1 = __expf(lrelu_f(esv.y + edv.y)) * r1;
                acc = fdot2f(h1[(size_t)s * 64 + lane], pack_half2(a0, a1), acc);
            }
            xs[(w * 2 + it) * 64 + lane] = elu_f(acc + b1[lane]);
        } else {
            xs[(w * 2 + it) * 64 + lane] = 0.f;
        }
    }
    __syncthreads();

    // ---- phase B (R10 transform2 body, verbatim structure) ----
    int h = tid >> 7, o = tid & 127;
    float acc[8];
    #pragma unroll
    for (int j = 0; j < 8; ++j) acc[j] = 0.f;
    const float* wp = W + h * (64 * 128) + o;
    for (int c = 0; c < 64; ++c) {
        float wv = wp[c * 128];
        #pragma unroll
        for (int j = 0; j < 8; ++j) acc[j] = fmaf(xs[j * 64 + c], wv, acc[j]);
    }
    #pragma unroll
    for (int j = 0; j < 8; ++j) {
        int n = n0 + j;
        if (n < N) h2[(size_t)n * 256 + 2 * o + h] = __float2half(acc[j]);
    }
    if (tid < 32) {
        int n = tid >> 2, r = tid & 3, hh = r >> 1, isd = r & 1;
        const float* wv = (isd ? wd2 : wa2) + hh * 64;
        float s = 0.f;
        #pragma unroll
        for (int c = 0; c < 64; ++c) s = fmaf(xs[n * 64 + c], wv[c], s);
        int nn = n0 + n;
        if (nn < N) { if (isd) ed2[nn * 2 + hh] = s; else es2[nn * 2 + hh] = s; }
    }
}

// ---------------- aggregation layer2: one wave per dst node, no segment-max ----------------
__global__ __launch_bounds__(256) void gat_agg2(
        const int* __restrict__ ofs, const int* __restrict__ sperm,
        const float* __restrict__ es, const float* __restrict__ ed,
        const uint2* __restrict__ h2, const float* __restrict__ b2,
        float* __restrict__ g2, int N) {
    __shared__ uint2 meta[4][64];
    int w = threadIdx.x >> 6;
    int d = blockIdx.x * 4 + w;
    if (d >= N) return;
    int lane = threadIdx.x & 63;
    int beg = ofs[d], end = ofs[d + 1];
    int deg = end - beg;
    float2 edv = *reinterpret_cast<const float2*>(ed + (size_t)d * 2);

    int s_f = 0;
    float ex0 = 0.f, ex1 = 0.f;
    int i0 = beg + lane;
    if (i0 < end) {
        s_f = sperm[i0];
        float2 esv = *reinterpret_cast<const float2*>(es + (size_t)s_f * 2);
        ex0 = __expf(lrelu_f(esv.x + edv.x));
        ex1 = __expf(lrelu_f(esv.y + edv.y));
    }
    float s0 = ex0, s1 = ex1;
    for (int i = i0 + 64; i < end; i += 64) {
        int s = sperm[i];
        float2 esv = *reinterpret_cast<const float2*>(es + (size_t)s * 2);
        s0 += __expf(lrelu_f(esv.x + edv.x));
        s1 += __expf(lrelu_f(esv.y + edv.y));
    }
    s0 = waveReduceSum(s0);
    s1 = waveReduceSum(s1);
    float r0 = 0.5f / (s0 + GAT_EPS), r1 = 0.5f / (s1 + GAT_EPS);
    int jmax = deg < 64 ? deg : 64;
    if (lane < jmax)
        meta[w][lane] = make_uint2((unsigned int)s_f, pack_half2(ex0 * r0, ex1 * r1));

    float acc0 = 0.f, acc1 = 0.f;   // channels 2*lane, 2*lane+1
    int j = 0;
    for (; j + 4 <= jmax; j += 4) {
        uint2 mm[4]; uint2 vv[4];
        #pragma unroll
        for (int k = 0; k < 4; ++k) mm[k] = meta[w][j + k];
        #pragma unroll
        for (int k = 0; k < 4; ++k) vv[k] = h2[(size_t)mm[k].x * 64 + lane];
        #pragma unroll
        for (int k = 0; k < 4; ++k) {
            acc0 = fdot2f(vv[k].x, mm[k].y, acc0);
            acc1 = fdot2f(vv[k].y, mm[k].y, acc1);
        }
    }
    for (; j < jmax; ++j) {
        uint2 m = meta[w][j];
        uint2 v = h2[(size_t)m.x * 64 + lane];
        acc0 = fdot2f(v.x, m.y, acc0);
        acc1 = fdot2f(v.y, m.y, acc1);
    }
    for (int i = beg + 64; i < end; ++i) {  // rare: deg > 64
        int s = sperm[i];
        float2 esv = *reinterpret_cast<const float2*>(es + (size_t)s * 2);
        float a0 = __expf(lrelu_f(esv.x + edv.x)) * r0;
        float a1 = __expf(lrelu_f(esv.y + edv.y)) * r1;
        unsigned int ap = pack_half2(a0, a1);
        uint2 v = h2[(size_t)s * 64 + lane];
        acc0 = fdot2f(v.x, ap, acc0);
        acc1 = fdot2f(v.y, ap, acc1);
    }
    float2 bv = reinterpret_cast<const float2*>(b2)[lane];
    g2[(size_t)d * 128 + 2 * lane]     = elu_f(acc0 + bv.x);   // pre-activated for pool
    g2[(size_t)d * 128 + 2 * lane + 1] = elu_f(acc1 + bv.y);
}

// ---------------- pool: sorted-batch run accumulation (g2 pre-activated) ----------------
#define POOL_NPB 128
__global__ __launch_bounds__(256) void pool_kernel(
        const float* __restrict__ g2, const int* __restrict__ batch,
        float* __restrict__ sums, float* __restrict__ cnts, int N) {
    int n0 = blockIdx.x * POOL_NPB;
    int c = threadIdx.x & 127;
    int p = threadIdx.x >> 7;
    int nend = n0 + POOL_NPB; if (nend > N) nend = N;
    int n = n0 + p;
    if (n >= nend) return;
    int cur_b = batch[n];
    float acc = 0.f;
    int cnt = 0;
    for (; n < nend; n += 2) {
        int b = batch[n];
        if (b != cur_b) {
            atomicAdd(&sums[(size_t)cur_b * 128 + c], acc);
            if (c == 0) atomicAdd(&cnts[cur_b], (float)cnt);
            acc = 0.f; cnt = 0; cur_b = b;
        }
        acc += g2[(size_t)n * 128 + c];
        ++cnt;
    }
    atomicAdd(&sums[(size_t)cur_b * 128 + c], acc);
    if (c == 0) atomicAdd(&cnts[cur_b], (float)cnt);
}

// ---------------- final: out = (sums/cnt) @ lo_w + lo_b ----------------
__global__ void final_kernel(
        const float* __restrict__ sums, const float* __restrict__ cnts,
        const float* __restrict__ w, const float* __restrict__ b,
        float* __restrict__ out, int G) {
    int g = blockIdx.x;
    int k = threadIdx.x;
    if (k >= 24) return;
    float inv = 1.f / fmaxf(cnts[g], 1.f);
    float acc = b[k];
    #pragma unroll
    for (int c = 0; c < 128; ++c) acc = fmaf(sums[g * 128 + c] * inv, w[c * 24 + k], acc);
    out[g * 24 + k] = acc;
}

extern "C" void kernel_launch(void* const* d_in, const int* in_sizes, int n_in,
                              void* d_out, int out_size, void* d_ws, size_t ws_size,
                              hipStream_t stream) {
    const float* x      = (const float*)d_in[0];
    const int*   ei     = (const int*)d_in[1];
    const int*   batch  = (const int*)d_in[2];
    const float* fc0_w  = (const float*)d_in[3];
    const float* fc0_b  = (const float*)d_in[4];
    const float* W1     = (const float*)d_in[5];
    const float* a_src1 = (const float*)d_in[6];
    const float* a_dst1 = (const float*)d_in[7];
    const float* b1     = (const float*)d_in[8];
    const float* W2     = (const float*)d_in[9];
    const float* a_src2 = (const float*)d_in[10];
    const float* a_dst2 = (const float*)d_in[11];
    const float* b2     = (const float*)d_in[12];
    const float* lo_w   = (const float*)d_in[13];
    const float* lo_b   = (const float*)d_in[14];
    float* out = (float*)d_out;

    const int N = in_sizes[0] / 16;
    const int E = in_sizes[1] / 2;
    const int G = out_size / 24;
    const int* src = ei;
    const int* dst = ei + E;
    const int nb = (N + 255) / 256;

    char* wsb = (char*)d_ws;
    size_t off = 0;
    auto allocf = [&](size_t n) { float* p = (float*)(wsb + off); off += ((n * 4 + 255) & ~(size_t)255); return p; };
    auto alloci = [&](size_t n) { int* p = (int*)(wsb + off); off += ((n * 4 + 255) & ~(size_t)255); return p; };
    auto alloch = [&](size_t n) { __half* p = (__half*)(wsb + off); off += ((n * 2 + 255) & ~(size_t)255); return p; };
    __half* h1buf = alloch((size_t)N * 128);   // layer1 table (distinct from h2 — gat_mid overlaps phases)
    __half* h2buf = alloch((size_t)N * 256);   // layer2 table
    float*  g2    = allocf((size_t)N * 128);
    float*  es1   = allocf((size_t)N * 2);
    float*  ed1   = allocf((size_t)N * 2);
    float*  es2   = allocf((size_t)N * 2);
    float*  ed2   = allocf((size_t)N * 2);
    float*  sums  = allocf((size_t)G * 128);
    float*  cnts  = allocf((size_t)G);
    float*  wa1   = allocf(64);
    float*  wd1   = allocf(64);
    float*  wa2   = allocf(128);
    float*  wd2   = allocf(128);
    int* deg     = alloci((size_t)N);
    int* ofs     = alloci((size_t)N + 1);
    int* cursor  = alloci((size_t)N);
    int* sperm   = alloci((size_t)E);
    int* bsum    = alloci((size_t)nb);
    int* bofs    = alloci((size_t)nb);
    (void)ws_size;

    // init (+ folded attention vectors in last block) + CSR build
    init_kernel<<<(N + 255) / 256, 256, 0, stream>>>(deg, sums, cnts, N, G,
            W1, a_src1, a_dst1, W2, a_src2, a_dst2, wa1, wd1, wa2, wd2);
    hist_kernel<<<(E + 255) / 256, 256, 0, stream>>>(dst, deg, E);
    scan_blocks_kernel<<<nb, 256, 0, stream>>>(deg, ofs, bsum, N);
    scan_bsum_kernel<<<1, 1024, 0, stream>>>(bsum, bofs, ofs + N, nb);
    scan_add_kernel<<<nb, 256, 0, stream>>>(ofs, bofs, cursor, N);
    scatter_kernel<<<(E + 255) / 256, 256, 0, stream>>>(src, dst, cursor, sperm, E);

    // ---- GAT layer 1 transform (fc0 fused) ----
    fused_t1<<<(N + 7) / 8, 256, 0, stream>>>(x, fc0_w, fc0_b, W1, wa1, wd1, h1buf, es1, ed1, N);

    // ---- fused agg-layer1 + transform-layer2 ----
    gat_mid<<<(N + 7) / 8, 256, 0, stream>>>(ofs, sperm, es1, ed1,
            (const unsigned int*)h1buf, b1, W2, wa2, wd2, h2buf, es2, ed2, N);

    // ---- GAT layer 2 aggregation ----
    gat_agg2<<<(N + 3) / 4, 256, 0, stream>>>(ofs, sperm, es2, ed2, (const uint2*)h2buf, b2, g2, N);

    // ---- pool + final linear ----
    pool_kernel<<<(N + POOL_NPB - 1) / POOL_NPB, 256, 0, stream>>>(g2, batch, sums, cnts, N);
    final_kernel<<<G, 32, 0, stream>>>(sums, cnts, lo_w, lo_b, out, G);
}

// Round 14
// 368.234 us; speedup vs baseline: 1.0326x; 1.0326x over previous
//
#include <hip/hip_runtime.h>
#include <hip/hip_fp16.h>
#include <math.h>

#define NEG_SLOPE 0.2f
#define GAT_EPS 1e-16f

__device__ __forceinline__ float elu_f(float x) { return x > 0.f ? x : expm1f(x); }
__device__ __forceinline__ float lrelu_f(float x) { return x > 0.f ? x : NEG_SLOPE * x; }

typedef _Float16 half2v __attribute__((ext_vector_type(2)));

// fp32 accumulate of half2 dot: acc += v.x*a.x + v.y*a.y
__device__ __forceinline__ float fdot2f(unsigned int v, unsigned int a, float acc) {
#if __has_builtin(__builtin_amdgcn_fdot2)
    return __builtin_amdgcn_fdot2(__builtin_bit_cast(half2v, v),
                                  __builtin_bit_cast(half2v, a), acc, false);
#else
    __half2 hv = __builtin_bit_cast(__half2, v);
    __half2 ha = __builtin_bit_cast(__half2, a);
    float2 fv = __half22float2(hv), fa = __half22float2(ha);
    return fmaf(fv.x, fa.x, fmaf(fv.y, fa.y, acc));
#endif
}

__device__ __forceinline__ unsigned int pack_half2(float a, float b) {
    __half2 h = __floats2half2_rn(a, b);
    return __builtin_bit_cast(unsigned int, h);
}

__device__ __forceinline__ float waveReduceSum(float v) {
    #pragma unroll
    for (int off = 32; off > 0; off >>= 1) v += __shfl_xor(v, off, 64);
    return v;
}

// ---------------- init: zero deg/sums/cnts; last block also folds attention vectors ----------------
__global__ void init_kernel(int* deg, float* sums, float* cnts, int N, int G,
        const float* __restrict__ W1, const float* __restrict__ as1, const float* __restrict__ ad1,
        const float* __restrict__ W2, const float* __restrict__ as2, const float* __restrict__ ad2,
        float* __restrict__ wa1, float* __restrict__ wd1,
        float* __restrict__ wa2, float* __restrict__ wd2) {
    int i = blockIdx.x * 256 + threadIdx.x;
    if (i < N) deg[i] = 0;
    if (i < G * 128) sums[i] = 0.f;
    if (i < G) cnts[i] = 0.f;
    if (blockIdx.x == gridDim.x - 1) {
        int t = threadIdx.x;
        if (t < 64) {                      // layer1: h=t>>5, c=t&31
            int h = t >> 5, c = t & 31;
            const float* w = W1 + (h * 32 + c) * 64;
            float sa = 0.f, sd = 0.f;
            for (int o = 0; o < 64; ++o) {
                sa = fmaf(w[o], as1[h * 64 + o], sa);
                sd = fmaf(w[o], ad1[h * 64 + o], sd);
            }
            wa1[t] = sa; wd1[t] = sd;
        } else if (t < 192) {              // layer2: u=t-64, h=u>>6, c=u&63
            int u = t - 64, h = u >> 6, c = u & 63;
            const float* w = W2 + (h * 64 + c) * 128;
            float sa = 0.f, sd = 0.f;
            for (int o = 0; o < 128; ++o) {
                sa = fmaf(w[o], as2[h * 128 + o], sa);
                sd = fmaf(w[o], ad2[h * 128 + o], sd);
            }
            wa2[u] = sa; wd2[u] = sd;
        }
    }
}

// ---------------- CSR build ----------------
__global__ __launch_bounds__(256) void hist_kernel(const int* __restrict__ dst,
                                                   int* __restrict__ deg, int E) {
    int e = blockIdx.x * 256 + threadIdx.x;
    if (e < E) atomicAdd(&deg[dst[e]], 1);
}

__global__ __launch_bounds__(256) void scan_blocks_kernel(const int* __restrict__ deg,
        int* __restrict__ ofs, int* __restrict__ bsum, int N) {
    __shared__ int wtot[4];
    int tid = threadIdx.x, lane = tid & 63, wid = tid >> 6;
    int i = blockIdx.x * 256 + tid;
    int v = (i < N) ? deg[i] : 0;
    int incl = v;
    #pragma unroll
    for (int off = 1; off < 64; off <<= 1) {
        int t = __shfl_up(incl, off, 64);
        if (lane >= off) incl += t;
    }
    if (lane == 63) wtot[wid] = incl;
    __syncthreads();
    int woff = 0;
    #pragma unroll
    for (int w = 0; w < 4; ++w) if (w < wid) woff += wtot[w];
    int excl = incl - v + woff;
    if (i < N) ofs[i] = excl;
    if (tid == 255) bsum[blockIdx.x] = woff + incl;
}

__global__ __launch_bounds__(1024) void scan_bsum_kernel(const int* __restrict__ bsum,
        int* __restrict__ bofs, int* __restrict__ ofsN, int nb) {
    __shared__ int wsum[16];
    int tid = threadIdx.x, lane = tid & 63, wid = tid >> 6;
    int v = (tid < nb) ? bsum[tid] : 0;
    int incl = v;
    #pragma unroll
    for (int off = 1; off < 64; off <<= 1) {
        int t = __shfl_up(incl, off, 64);
        if (lane >= off) incl += t;
    }
    if (lane == 63) wsum[wid] = incl;
    __syncthreads();
    if (wid == 0) {
        int wv = (lane < 16) ? wsum[lane] : 0;
        int winc = wv;
        #pragma unroll
        for (int off = 1; off < 16; off <<= 1) {
            int t = __shfl_up(winc, off, 64);
            if (lane >= off) winc += t;
        }
        if (lane < 16) wsum[lane] = winc - wv;
    }
    __syncthreads();
    int excl = incl - v + wsum[wid];
    if (tid < nb) bofs[tid] = excl;
    if (tid == nb - 1) *ofsN = excl + v;
}

__global__ __launch_bounds__(256) void scan_add_kernel(int* __restrict__ ofs,
        const int* __restrict__ bofs, int* __restrict__ cursor, int N) {
    int i = blockIdx.x * 256 + threadIdx.x;
    if (i < N) {
        int v = ofs[i] + bofs[blockIdx.x];
        ofs[i] = v;
        cursor[i] = v;
    }
}

__global__ __launch_bounds__(256) void scatter_kernel(
        const int* __restrict__ src, const int* __restrict__ dst,
        int* __restrict__ cursor, int* __restrict__ sperm, int E) {
    int e = blockIdx.x * 256 + threadIdx.x;
    if (e >= E) return;
    int d = dst[e];
    int pos = atomicAdd(&cursor[d], 1);
    sperm[pos] = src[e];
}

// ---------------- fused fc0 + GAT layer1 transform (8 nodes/block) ----------------
__global__ __launch_bounds__(256) void fused_t1(
        const float* __restrict__ x, const float* __restrict__ w0,
        const float* __restrict__ b0, const float* __restrict__ W1,
        const float* __restrict__ wa1, const float* __restrict__ wd1,
        __half* __restrict__ h1, float* __restrict__ es, float* __restrict__ ed, int N) {
    __shared__ float xs[8 * 16];
    __shared__ float hs[8 * 32];
    int n0 = blockIdx.x * 8;
    int tid = threadIdx.x;
    if (tid < 128) {
        int gi = n0 * 16 + tid;
        xs[tid] = (gi < N * 16) ? x[gi] : 0.f;
    }
    __syncthreads();
    {
        int j = tid >> 5, o = tid & 31;
        float acc = b0[o];
        #pragma unroll
        for (int c = 0; c < 16; ++c) acc = fmaf(xs[j * 16 + c], w0[c * 32 + o], acc);
        hs[j * 32 + o] = elu_f(acc);
    }
    __syncthreads();
    int o = tid & 63, h = (tid >> 6) & 1, nh = tid >> 7;
    float acc[4];
    #pragma unroll
    for (int j = 0; j < 4; ++j) acc[j] = 0.f;
    const float* wp = W1 + h * (32 * 64) + o;
    #pragma unroll
    for (int c = 0; c < 32; ++c) {
        float wv = wp[c * 64];
        #pragma unroll
        for (int j = 0; j < 4; ++j) acc[j] = fmaf(hs[(nh * 4 + j) * 32 + c], wv, acc[j]);
    }
    #pragma unroll
    for (int j = 0; j < 4; ++j) {
        int n = n0 + nh * 4 + j;
        if (n < N) h1[(size_t)n * 128 + 2 * o + h] = __float2half(acc[j]);
    }
    if (tid < 32) {
        int n = tid >> 2, r = tid & 3, hh = r >> 1, isd = r & 1;
        const float* wv = (isd ? wd1 : wa1) + hh * 32;
        float s = 0.f;
        #pragma unroll
        for (int c = 0; c < 32; ++c) s = fmaf(hs[n * 32 + c], wv[c], s);
        int nn = n0 + n;
        if (nn < N) { if (isd) ed[nn * 2 + hh] = s; else es[nn * 2 + hh] = s; }
    }
}

// ---------------- GAT layer2 transform (8 nodes/block) ----------------
__global__ __launch_bounds__(256) void gat_transform2(
        const float* __restrict__ g1, const float* __restrict__ W,
        const float* __restrict__ wa2, const float* __restrict__ wd2,
        __half* __restrict__ h2, float* __restrict__ es, float* __restrict__ ed, int N) {
    __shared__ float xs[8 * 64];
    int n0 = blockIdx.x * 8;
    int tid = threadIdx.x;
    for (int idx = tid; idx < 8 * 64; idx += 256) {
        int gi = n0 * 64 + idx;
        xs[idx] = (gi < N * 64) ? g1[gi] : 0.f;
    }
    __syncthreads();
    int h = tid >> 7, o = tid & 127;
    float acc[8];
    #pragma unroll
    for (int j = 0; j < 8; ++j) acc[j] = 0.f;
    const float* wp = W + h * (64 * 128) + o;
    for (int c = 0; c < 64; ++c) {
        float wv = wp[c * 128];
        #pragma unroll
        for (int j = 0; j < 8; ++j) acc[j] = fmaf(xs[j * 64 + c], wv, acc[j]);
    }
    #pragma unroll
    for (int j = 0; j < 8; ++j) {
        int n = n0 + j;
        if (n < N) h2[(size_t)n * 256 + 2 * o + h] = __float2half(acc[j]);
    }
    if (tid < 32) {
        int n = tid >> 2, r = tid & 3, hh = r >> 1, isd = r & 1;
        const float* wv = (isd ? wd2 : wa2) + hh * 64;
        float s = 0.f;
        #pragma unroll
        for (int c = 0; c < 64; ++c) s = fmaf(xs[n * 64 + c], wv[c], s);
        int nn = n0 + n;
        if (nn < N) { if (isd) ed[nn * 2 + hh] = s; else es[nn * 2 + hh] = s; }
    }
}

// ---------------- aggregation layer1: one wave per dst node, no segment-max ----------------
// (exact: softmax is shift-invariant; |e| is O(1) so exp cannot overflow)
__global__ __launch_bounds__(256) void gat_agg1(
        const int* __restrict__ ofs, const int* __restrict__ sperm,
        const float* __restrict__ es, const float* __restrict__ ed,
        const unsigned int* __restrict__ h1, const float* __restrict__ b1,
        float* __restrict__ g1, int N) {
    __shared__ uint2 meta[4][64];
    int w = threadIdx.x >> 6;
    int d = blockIdx.x * 4 + w;
    if (d >= N) return;
    int lane = threadIdx.x & 63;
    int beg = ofs[d], end = ofs[d + 1];
    int deg = end - beg;
    float2 edv = *reinterpret_cast<const float2*>(ed + (size_t)d * 2);

    int s_f = 0;
    float ex0 = 0.f, ex1 = 0.f;
    int i0 = beg + lane;
    if (i0 < end) {
        s_f = sperm[i0];
        float2 esv = *reinterpret_cast<const float2*>(es + (size_t)s_f * 2);
        ex0 = __expf(lrelu_f(esv.x + edv.x));
        ex1 = __expf(lrelu_f(esv.y + edv.y));
    }
    float s0 = ex0, s1 = ex1;
    for (int i = i0 + 64; i < end; i += 64) {
        int s = sperm[i];
        float2 esv = *reinterpret_cast<const float2*>(es + (size_t)s * 2);
        s0 += __expf(lrelu_f(esv.x + edv.x));
        s1 += __expf(lrelu_f(esv.y + edv.y));
    }
    s0 = waveReduceSum(s0);
    s1 = waveReduceSum(s1);
    float r0 = 0.5f / (s0 + GAT_EPS), r1 = 0.5f / (s1 + GAT_EPS);
    int jmax = deg < 64 ? deg : 64;
    if (lane < jmax)
        meta[w][lane] = make_uint2((unsigned int)s_f, pack_half2(ex0 * r0, ex1 * r1));
    // wave-internal LDS write->read; compiler inserts lgkmcnt wait, no barrier needed

    float acc = 0.f;
    int j = 0;
    for (; j + 4 <= jmax; j += 4) {
        uint2 mm[4]; unsigned int vv[4];
        #pragma unroll
        for (int k = 0; k < 4; ++k) mm[k] = meta[w][j + k];
        #pragma unroll
        for (int k = 0; k < 4; ++k) vv[k] = h1[(size_t)mm[k].x * 64 + lane];
        #pragma unroll
        for (int k = 0; k < 4; ++k) acc = fdot2f(vv[k], mm[k].y, acc);
    }
    for (; j < jmax; ++j) {
        uint2 m = meta[w][j];
        acc = fdot2f(h1[(size_t)m.x * 64 + lane], m.y, acc);
    }
    for (int i = beg + 64; i < end; ++i) {  // rare: deg > 64
        int s = sperm[i];
        float2 esv = *reinterpret_cast<const float2*>(es + (size_t)s * 2);
        float a0 = __expf(lrelu_f(esv.x + edv.x)) * r0;
        float a1 = __expf(lrelu_f(esv.y + edv.y)) * r1;
        acc = fdot2f(h1[(size_t)s * 64 + lane], pack_half2(a0, a1), acc);
    }
    g1[(size_t)d * 64 + lane] = elu_f(acc + b1[lane]);   // pre-activate for transform2
}

// ---------------- aggregation layer2: one wave per dst node, no segment-max ----------------
__global__ __launch_bounds__(256) void gat_agg2(
        const int* __restrict__ ofs, const int* __restrict__ sperm,
        const float* __restrict__ es, const float* __restrict__ ed,
        const uint2* __restrict__ h2, const float* __restrict__ b2,
        float* __restrict__ g2, int N) {
    __shared__ uint2 meta[4][64];
    int w = threadIdx.x >> 6;
    int d = blockIdx.x * 4 + w;
    if (d >= N) return;
    int lane = threadIdx.x & 63;
    int beg = ofs[d], end = ofs[d + 1];
    int deg = end - beg;
    float2 edv = *reinterpret_cast<const float2*>(ed + (size_t)d * 2);

    int s_f = 0;
    float ex0 = 0.f, ex1 = 0.f;
    int i0 = beg + lane;
    if (i0 < end) {
        s_f = sperm[i0];
        float2 esv = *reinterpret_cast<const float2*>(es + (size_t)s_f * 2);
        ex0 = __expf(lrelu_f(esv.x + edv.x));
        ex1 = __expf(lrelu_f(esv.y + edv.y));
    }
    float s0 = ex0, s1 = ex1;
    for (int i = i0 + 64; i < end; i += 64) {
        int s = sperm[i];
        float2 esv = *reinterpret_cast<const float2*>(es + (size_t)s * 2);
        s0 += __expf(lrelu_f(esv.x + edv.x));
        s1 += __expf(lrelu_f(esv.y + edv.y));
    }
    s0 = waveReduceSum(s0);
    s1 = waveReduceSum(s1);
    float r0 = 0.5f / (s0 + GAT_EPS), r1 = 0.5f / (s1 + GAT_EPS);
    int jmax = deg < 64 ? deg : 64;
    if (lane < jmax)
        meta[w][lane] = make_uint2((unsigned int)s_f, pack_half2(ex0 * r0, ex1 * r1));

    float acc0 = 0.f, acc1 = 0.f;   // channels 2*lane, 2*lane+1
    int j = 0;
    for (; j + 4 <= jmax; j += 4) {
        uint2 mm[4]; uint2 vv[4];
        #pragma unroll
        for (int k = 0; k < 4; ++k) mm[k] = meta[w][j + k];
        #pragma unroll
        for (int k = 0; k < 4; ++k) vv[k] = h2[(size_t)mm[k].x * 64 + lane];
        #pragma unroll
        for (int k = 0; k < 4; ++k) {
            acc0 = fdot2f(vv[k].x, mm[k].y, acc0);
            acc1 = fdot2f(vv[k].y, mm[k].y, acc1);
        }
    }
    for (; j < jmax; ++j) {
        uint2 m = meta[w][j];
        uint2 v = h2[(size_t)m.x * 64 + lane];
        acc0 = fdot2f(v.x, m.y, acc0);
        acc1 = fdot2f(v.y, m.y, acc1);
    }
    for (int i = beg + 64; i < end; ++i) {  // rare: deg > 64
        int s = sperm[i];
        float2 esv = *reinterpret_cast<const float2*>(es + (size_t)s * 2);
        float a0 = __expf(lrelu_f(esv.x + edv.x)) * r0;
        float a1 = __expf(lrelu_f(esv.y + edv.y)) * r1;
        unsigned int ap = pack_half2(a0, a1);
        uint2 v = h2[(size_t)s * 64 + lane];
        acc0 = fdot2f(v.x, ap, acc0);
        acc1 = fdot2f(v.y, ap, acc1);
    }
    float2 bv = reinterpret_cast<const float2*>(b2)[lane];
    g2[(size_t)d * 128 + 2 * lane]     = elu_f(acc0 + bv.x);   // pre-activated for pool
    g2[(size_t)d * 128 + 2 * lane + 1] = elu_f(acc1 + bv.y);
}

// ---------------- pool: sorted-batch run accumulation (g2 pre-activated) ----------------
#define POOL_NPB 128
__global__ __launch_bounds__(256) void pool_kernel(
        const float* __restrict__ g2, const int* __restrict__ batch,
        float* __restrict__ sums, float* __restrict__ cnts, int N) {
    int n0 = blockIdx.x * POOL_NPB;
    int c = threadIdx.x & 127;
    int p = threadIdx.x >> 7;
    int nend = n0 + POOL_NPB; if (nend > N) nend = N;
    int n = n0 + p;
    if (n >= nend) return;
    int cur_b = batch[n];
    float acc = 0.f;
    int cnt = 0;
    for (; n < nend; n += 2) {
        int b = batch[n];
        if (b != cur_b) {
            atomicAdd(&sums[(size_t)cur_b * 128 + c], acc);
            if (c == 0) atomicAdd(&cnts[cur_b], (float)cnt);
            acc = 0.f; cnt = 0; cur_b = b;
        }
        acc += g2[(size_t)n * 128 + c];
        ++cnt;
    }
    atomicAdd(&sums[(size_t)cur_b * 128 + c], acc);
    if (c == 0) atomicAdd(&cnts[cur_b], (float)cnt);
}

// ---------------- final: out = (sums/cnt) @ lo_w + lo_b ----------------
__global__ void final_kernel(
        const float* __restrict__ sums, const float* __restrict__ cnts,
        const float* __restrict__ w, const float* __restrict__ b,
        float* __restrict__ out, int G) {
    int g = blockIdx.x;
    int k = threadIdx.x;
    if (k >= 24) return;
    float inv = 1.f / fmaxf(cnts[g], 1.f);
    float acc = b[k];
    #pragma unroll
    for (int c = 0; c < 128; ++c) acc = fmaf(sums[g * 128 + c] * inv, w[c * 24 + k], acc);
    out[g * 24 + k] = acc;
}

extern "C" void kernel_launch(void* const* d_in, const int* in_sizes, int n_in,
                              void* d_out, int out_size, void* d_ws, size_t ws_size,
                              hipStream_t stream) {
    const float* x      = (const float*)d_in[0];
    const int*   ei     = (const int*)d_in[1];
    const int*   batch  = (const int*)d_in[2];
    const float* fc0_w  = (const float*)d_in[3];
    const float* fc0_b  = (const float*)d_in[4];
    const float* W1     = (const float*)d_in[5];
    const float* a_src1 = (const float*)d_in[6];
    const float* a_dst1 = (const float*)d_in[7];
    const float* b1     = (const float*)d_in[8];
    const float* W2     = (const float*)d_in[9];
    const float* a_src2 = (const float*)d_in[10];
    const float* a_dst2 = (const float*)d_in[11];
    const float* b2     = (const float*)d_in[12];
    const float* lo_w   = (const float*)d_in[13];
    const float* lo_b   = (const float*)d_in[14];
    float* out = (float*)d_out;

    const int N = in_sizes[0] / 16;
    const int E = in_sizes[1] / 2;
    const int G = out_size / 24;
    const int* src = ei;
    const int* dst = ei + E;
    const int nb = (N + 255) / 256;

    char* wsb = (char*)d_ws;
    size_t off = 0;
    auto allocf = [&](size_t n) { float* p = (float*)(wsb + off); off += ((n * 4 + 255) & ~(size_t)255); return p; };
    auto alloci = [&](size_t n) { int* p = (int*)(wsb + off); off += ((n * 4 + 255) & ~(size_t)255); return p; };
    auto alloch = [&](size_t n) { __half* p = (__half*)(wsb + off); off += ((n * 2 + 255) & ~(size_t)255); return p; };
    __half* hbuf  = alloch((size_t)N * 256);   // h1 uses N*128 halves; h2 uses N*256 halves
    float*  g1    = allocf((size_t)N * 64);
    float*  g2    = allocf((size_t)N * 128);
    float*  es    = allocf((size_t)N * 2);
    float*  ed    = allocf((size_t)N * 2);
    float*  sums  = allocf((size_t)G * 128);
    float*  cnts  = allocf((size_t)G);
    float*  wa1   = allocf(64);
    float*  wd1   = allocf(64);
    float*  wa2   = allocf(128);
    float*  wd2   = allocf(128);
    int* deg     = alloci((size_t)N);
    int* ofs     = alloci((size_t)N + 1);
    int* cursor  = alloci((size_t)N);
    int* sperm   = alloci((size_t)E);
    int* bsum    = alloci((size_t)nb);
    int* bofs    = alloci((size_t)nb);
    (void)ws_size;

    // init (+ folded attention vectors in last block) + CSR build
    init_kernel<<<(N + 255) / 256, 256, 0, stream>>>(deg, sums, cnts, N, G,
            W1, a_src1, a_dst1, W2, a_src2, a_dst2, wa1, wd1, wa2, wd2);
    hist_kernel<<<(E + 255) / 256, 256, 0, stream>>>(dst, deg, E);
    scan_blocks_kernel<<<nb, 256, 0, stream>>>(deg, ofs, bsum, N);
    scan_bsum_kernel<<<1, 1024, 0, stream>>>(bsum, bofs, ofs + N, nb);
    scan_add_kernel<<<nb, 256, 0, stream>>>(ofs, bofs, cursor, N);
    scatter_kernel<<<(E + 255) / 256, 256, 0, stream>>>(src, dst, cursor, sperm, E);

    // ---- GAT layer 1 (fc0 fused into transform) ----
    fused_t1<<<(N + 7) / 8, 256, 0, stream>>>(x, fc0_w, fc0_b, W1, wa1, wd1, hbuf, es, ed, N);
    gat_agg1<<<(N + 3) / 4, 256, 0, stream>>>(ofs, sperm, es, ed, (const unsigned int*)hbuf, b1, g1, N);

    // ---- GAT layer 2 ----
    gat_transform2<<<(N + 7) / 8, 256, 0, stream>>>(g1, W2, wa2, wd2, hbuf, es, ed, N);
    gat_agg2<<<(N + 3) / 4, 256, 0, stream>>>(ofs, sperm, es, ed, (const uint2*)hbuf, b2, g2, N);

    // ---- pool + final linear ----
    pool_kernel<<<(N + POOL_NPB - 1) / POOL_NPB, 256, 0, stream>>>(g2, batch, sums, cnts, N);
    final_kernel<<<G, 32, 0, stream>>>(sums, cnts, lo_w, lo_b, out, G);
}